// Round 19
// baseline (1894.033 us; speedup 1.0000x reference)
//
#include <hip/hip_runtime.h>
#include <hip/hip_bf16.h>

#define Bb 4
#define Tt 256
#define Uu 128
#define H1 512
#define H2 640
#define Dd 640
#define V1c 1025

typedef __bf16 bf16x8 __attribute__((ext_vector_type(8)));
typedef unsigned short ushort8 __attribute__((ext_vector_type(8)));
typedef unsigned short ushort4v __attribute__((ext_vector_type(4)));
typedef float floatx4 __attribute__((ext_vector_type(4)));

static __device__ __forceinline__ unsigned short f2bf(float x) {
    union { float f; unsigned u; } a; a.f = x;
    unsigned r = a.u + 0x7fffu + ((a.u >> 16) & 1u);
    return (unsigned short)(r >> 16);
}
static __device__ __forceinline__ float bf2f(unsigned short x) {
    union { unsigned u; float f; } a; a.u = ((unsigned)x) << 16; return a.f;
}

// ---------------- prep: fg linears (blocks 0..191) + Wb2 swizzle (192..351) ----------------
__global__ __launch_bounds__(640) void prep(const float* __restrict__ enc,
                                            const float* __restrict__ Wenc,
                                            const float* __restrict__ benc,
                                            float* __restrict__ f,
                                            const float* __restrict__ pred,
                                            const float* __restrict__ Wpred,
                                            const float* __restrict__ bpred,
                                            float* __restrict__ g,
                                            const float* __restrict__ Wout,
                                            unsigned short* __restrict__ Wb2,
                                            float* __restrict__ wtail) {
    __shared__ __align__(16) float sh[640 * 8];
    const int tid = threadIdx.x;

    if (blockIdx.x < 192) {
        const bool isF = blockIdx.x < 128;
        const float* in   = isF ? enc : pred;
        const float* W    = isF ? Wenc : Wpred;
        const float* bias = isF ? benc : bpred;
        float* out        = isF ? f : g;
        const int H    = isF ? H1 : H2;
        const int Tdim = isF ? Tt : Uu;
        const int blk  = isF ? (int)blockIdx.x : (int)blockIdx.x - 128;
        const int tBlocks = Tdim >> 3;
        const int b  = blk / tBlocks;
        const int t0 = (blk % tBlocks) << 3;
        const float* inB = in + (size_t)b * H * Tdim + t0;

        for (int h = tid; h < H; h += 640) {
            float4 v0 = *(const float4*)(inB + (size_t)h * Tdim);
            float4 v1 = *(const float4*)(inB + (size_t)h * Tdim + 4);
            *(float4*)(&sh[h * 8])     = v0;
            *(float4*)(&sh[h * 8 + 4]) = v1;
        }
        __syncthreads();

        const int d = tid;
        float acc[8];
        #pragma unroll
        for (int j = 0; j < 8; ++j) acc[j] = 0.f;
        #pragma unroll 4
        for (int h = 0; h < H; ++h) {
            float w = W[(size_t)h * Dd + d];
            float4 s0 = *(const float4*)(&sh[h * 8]);
            float4 s1 = *(const float4*)(&sh[h * 8 + 4]);
            acc[0] += s0.x * w; acc[1] += s0.y * w; acc[2] += s0.z * w; acc[3] += s0.w * w;
            acc[4] += s1.x * w; acc[5] += s1.y * w; acc[6] += s1.z * w; acc[7] += s1.w * w;
        }
        float bv = bias[d];
        float* o = out + ((size_t)b * Tdim + t0) * Dd + d;
        #pragma unroll
        for (int j = 0; j < 8; ++j) o[(size_t)j * Dd] = acc[j] + bv;
    } else {
        float (*tile)[129] = (float(*)[129])sh;    // 32 x 129 (padded)
        const int blk2 = blockIdx.x - 192;         // 0..159
        const int w = blk2 / 20;
        const int db = blk2 % 20;

        for (int idx = tid; idx < 4096; idx += 640) {
            int d_loc = idx >> 7;
            int v_loc = idx & 127;
            tile[d_loc][v_loc] = Wout[(size_t)(db * 32 + d_loc) * V1c + w * 128 + v_loc];
        }
        __syncthreads();

        if (tid < 512) {
            int gidx = tid;
            int nt  = gidx >> 6;
            int rem = gidx & 63;
            int l15 = rem >> 2;
            int lg  = rem & 3;
            int v_loc = nt * 16 + l15;
            ushort8 pk;
            #pragma unroll
            for (int j = 0; j < 8; ++j) pk[j] = f2bf(tile[lg * 8 + j][v_loc]);
            *(ushort8*)(Wb2 + (size_t)w * 81920 + db * 4096 + gidx * 8) = pk;
        }
        if (blk2 == 0 && tid < Dd) wtail[tid] = Wout[(size_t)tid * V1c + 1024];
    }
}

// ---------------- fused joint + log-softmax ----------------
// 1024 blocks x 512 thr (8 waves); each block does BOTH u-halves of its (b,t).
// Per tile: R12 structure (full-panel stage, 20-step K-loop on Wb2, post-K tail
// dot, 4x16-row LDS-staged NT drain). Changes vs R12:
//  (1) single-sweep softmax (per-wave max+sumexp in one pass, exact LSE merge),
//  (2) sOut is a SEPARATE buffer (not aliased over hlds) so tile0's final NT
//      drain is issued-not-waited: tile1's staging barrier absorbs the wait.
__global__ __launch_bounds__(512) void joint_main(const float* __restrict__ f,
                                                  const float* __restrict__ g,
                                                  const unsigned short* __restrict__ Wb2,
                                                  const float* __restrict__ wtail,
                                                  const float* __restrict__ b_out,
                                                  float* __restrict__ out) {
    __shared__ __align__(16) unsigned short hlds[2 * 64 * 328];   // 83,968 B
    __shared__ __align__(16) float sOut[16 * 1025];               // 65,600 B
    __shared__ float wtld[640];
    __shared__ float sPartM[8 * 64];
    __shared__ float sPartS[8 * 64];
    __shared__ float sRed[64];
    __shared__ float sTail[64];

    const int tid = threadIdx.x;
    const int l = tid & 63;
    const int w = tid >> 6;
    const int l15 = l & 15;
    const int lg = l >> 4;

    const int blk = blockIdx.x;          // 0..1023 = (b, t)
    const int t = blk & 255;
    const int b = blk >> 8;
    const size_t fbase = ((size_t)b * Tt + t) * Dd;

    // stage wtail (fp32) into LDS
    for (int i = tid; i < Dd; i += 512) wtld[i] = wtail[i];

    const unsigned short* __restrict__ bbase = Wb2 + (size_t)w * 81920 + (l15 * 32 + lg * 8);
    const int srow = w * 8 + (l >> 3);
    const int ssub = l & 7;

    #pragma unroll 1
    for (int tile = 0; tile < 2; ++tile) {
        const int u0 = tile * 64;
        const size_t gbase = ((size_t)b * Uu + u0) * Dd;
        const size_t rowbase = (size_t)(b * Tt + t) * Uu + u0;

        floatx4 acc[4][8];
        #pragma unroll
        for (int i = 0; i < 4; ++i)
            #pragma unroll
            for (int j = 0; j < 8; ++j) acc[i][j] = (floatx4){0.f, 0.f, 0.f, 0.f};

        float tailAcc = 0.f;

        // ---- stage FULL h = relu(f+g) panel: 64 rows x 640 cols bf16 ----
        // (for tile 1 this overlaps tile 0's in-flight NT drain; barrier below
        //  absorbs both vmcnt waits in one stall)
        {
            const int row = tid >> 3;
            const float* frow = f + fbase;
            const float* grow = g + gbase + (size_t)row * Dd;
            #pragma unroll
            for (int j = 0; j < 20; ++j) {
                int c4 = (tid & 7) + 8 * j;        // float4 slot 0..159
                int d = c4 * 4;
                int half = (j >= 10) ? 1 : 0;
                int cloc = c4 - half * 80;
                float4 fv = *(const float4*)(frow + d);
                float4 gv = *(const float4*)(grow + d);
                float h0 = fv.x + gv.x; h0 = h0 > 0.f ? h0 : 0.f;
                float h1 = fv.y + gv.y; h1 = h1 > 0.f ? h1 : 0.f;
                float h2 = fv.z + gv.z; h2 = h2 > 0.f ? h2 : 0.f;
                float h3 = fv.w + gv.w; h3 = h3 > 0.f ? h3 : 0.f;
                ushort4v pk;
                pk.x = f2bf(h0); pk.y = f2bf(h1); pk.z = f2bf(h2); pk.w = f2bf(h3);
                *(ushort4v*)(&hlds[half * 20992 + row * 328 + cloc * 4]) = pk;
            }
        }
        __syncthreads();

        // ---- K loop: 20 steps of 32, B double-buffered in regs, no barriers ----
        {
            ushort8 Bbuf[2][8];
            #pragma unroll
            for (int nt = 0; nt < 8; ++nt)
                Bbuf[0][nt] = *(const ushort8*)(bbase + nt * 512);
            #pragma unroll
            for (int ksg = 0; ksg < 20; ++ksg) {
                if (ksg < 19) {
                    #pragma unroll
                    for (int nt = 0; nt < 8; ++nt)
                        Bbuf[(ksg + 1) & 1][nt] =
                            *(const ushort8*)(bbase + (ksg + 1) * 4096 + nt * 512);
                }
                const int bufo = (ksg >= 10) ? 20992 : 0;
                const int ks = (ksg >= 10) ? (ksg - 10) : ksg;
                bf16x8 afrag[4];
                #pragma unroll
                for (int mt = 0; mt < 4; ++mt) {
                    ushort8 av = *(const ushort8*)(&hlds[bufo + (mt * 16 + l15) * 328 + ks * 32 + lg * 8]);
                    afrag[mt] = __builtin_bit_cast(bf16x8, av);
                }
                #pragma unroll
                for (int nt = 0; nt < 8; ++nt) {
                    bf16x8 bfrag = __builtin_bit_cast(bf16x8, Bbuf[ksg & 1][nt]);
                    #pragma unroll
                    for (int mt = 0; mt < 4; ++mt) {
                        acc[mt][nt] = __builtin_amdgcn_mfma_f32_16x16x32_bf16(
                            afrag[mt], bfrag, acc[mt][nt], 0, 0, 0);
                    }
                }
            }
        }

        // ---- tail column: dot(h_row, wtail) from LDS ----
        #pragma unroll
        for (int j = 0; j < 20; ++j) {
            int c4 = ssub + 8 * j;                 // 0..159
            int half = (j >= 10) ? 1 : 0;
            int cloc = c4 - half * 80;
            ushort4v hv = *(const ushort4v*)(&hlds[half * 20992 + srow * 328 + cloc * 4]);
            float4 wv = *(const float4*)(&wtld[c4 * 4]);
            tailAcc += bf2f(hv.x) * wv.x + bf2f(hv.y) * wv.y +
                       bf2f(hv.z) * wv.z + bf2f(hv.w) * wv.w;
        }
        tailAcc += __shfl_xor(tailAcc, 1);
        tailAcc += __shfl_xor(tailAcc, 2);
        tailAcc += __shfl_xor(tailAcc, 4);
        if (ssub == 0) sTail[srow] = tailAcc + b_out[1024];

        // ---- + b_out ----
        #pragma unroll
        for (int nt = 0; nt < 8; ++nt) {
            float bo = b_out[w * 128 + nt * 16 + l15];
            #pragma unroll
            for (int mt = 0; mt < 4; ++mt)
                #pragma unroll
                for (int r = 0; r < 4; ++r) acc[mt][nt][r] += bo;
        }

        // ---- single-sweep softmax: per-wave (max, sumexp@max) in one pass ----
        #pragma unroll
        for (int mt = 0; mt < 4; ++mt) {
            #pragma unroll
            for (int r = 0; r < 4; ++r) {
                int row = mt * 16 + lg * 4 + r;
                float m = acc[mt][0][r];
                #pragma unroll
                for (int nt = 1; nt < 8; ++nt) m = fmaxf(m, acc[mt][nt][r]);
                #pragma unroll
                for (int msk = 1; msk < 16; msk <<= 1) m = fmaxf(m, __shfl_xor(m, msk));
                float sv = 0.f;
                #pragma unroll
                for (int nt = 0; nt < 8; ++nt) sv += __expf(acc[mt][nt][r] - m);
                #pragma unroll
                for (int msk = 1; msk < 16; msk <<= 1) sv += __shfl_xor(sv, msk);
                if (l15 == 0) { sPartM[w * 64 + row] = m; sPartS[w * 64 + row] = sv; }
            }
        }
        __syncthreads();   // sPartM/S + sTail visible

        if (tid < 64) {
            float tl = sTail[tid];
            float m = tl;
            #pragma unroll
            for (int c = 0; c < 8; ++c) m = fmaxf(m, sPartM[c * 64 + tid]);
            float sv = __expf(tl - m);
            #pragma unroll
            for (int c = 0; c < 8; ++c) sv += sPartS[c * 64 + tid] * __expf(sPartM[c * 64 + tid] - m);
            sRed[tid] = m + logf(sv);  // exact lse
        }
        __syncthreads();

        // ---- write: 4 groups of 16 rows, LDS-staged, NT float4 drain ----
        #pragma unroll
        for (int grp = 0; grp < 4; ++grp) {
            #pragma unroll
            for (int nt = 0; nt < 8; ++nt) {
                #pragma unroll
                for (int r = 0; r < 4; ++r) {
                    sOut[(lg * 4 + r) * 1025 + w * 128 + nt * 16 + l15] =
                        acc[grp][nt][r] - sRed[grp * 16 + lg * 4 + r];
                }
            }
            if (tid < 16) sOut[tid * 1025 + 1024] = sTail[grp * 16 + tid] - sRed[grp * 16 + tid];
            __syncthreads();
            // 16*1025 = 16400 floats = 4100 float4
            float* outp = out + (rowbase + grp * 16) * (size_t)V1c;
            #pragma unroll
            for (int k = 0; k < 8; ++k) {
                int i4 = tid + 512 * k;
                floatx4 v = *(const floatx4*)(&sOut[4 * i4]);
                __builtin_nontemporal_store(v, (floatx4*)(outp + 4 * i4));
            }
            if (tid < 4) {
                int i4 = tid + 4096;
                floatx4 v = *(const floatx4*)(&sOut[4 * i4]);
                __builtin_nontemporal_store(v, (floatx4*)(outp + 4 * i4));
            }
            // Skip the post-drain barrier on the LAST group: for tile 0 the
            // next writer of sOut is tile 1's FILL, which sits behind the
            // staging barrier (staging doesn't touch sOut; the barrier's
            // vmcnt drain covers these NT stores). For tile 1, kernel ends.
            if (grp < 3) __syncthreads();
        }
    }
}

extern "C" void kernel_launch(void* const* d_in, const int* in_sizes, int n_in,
                              void* d_out, int out_size, void* d_ws, size_t ws_size,
                              hipStream_t stream) {
    const float* enc   = (const float*)d_in[0];
    const float* pred  = (const float*)d_in[1];
    const float* Wenc  = (const float*)d_in[2];
    const float* benc  = (const float*)d_in[3];
    const float* Wpred = (const float*)d_in[4];
    const float* bpred = (const float*)d_in[5];
    const float* Wout  = (const float*)d_in[6];
    const float* bout  = (const float*)d_in[7];

    float* f = (float*)d_ws;                                     // 655360 f32
    float* g = f + (size_t)Bb * Tt * Dd;                         // 327680 f32
    unsigned short* Wb2 = (unsigned short*)(g + (size_t)Bb * Uu * Dd);  // 655360 u16
    float* wtail = (float*)(Wb2 + 8 * 81920);                    // 640 f32

    prep<<<352, 640, 0, stream>>>(enc, Wenc, benc, f, pred, Wpred, bpred, g,
                                  Wout, Wb2, wtail);
    joint_main<<<Bb * Tt, 512, 0, stream>>>(f, g, Wb2, wtail, bout, (float*)d_out);
}

// Round 20
// 365.457 us; speedup vs baseline: 5.1826x; 5.1826x over previous
//
#include <hip/hip_runtime.h>
#include <hip/hip_bf16.h>

#define Bb 4
#define Tt 256
#define Uu 128
#define H1 512
#define H2 640
#define Dd 640
#define V1c 1025

typedef __bf16 bf16x8 __attribute__((ext_vector_type(8)));
typedef unsigned short ushort8 __attribute__((ext_vector_type(8)));
typedef unsigned short ushort4v __attribute__((ext_vector_type(4)));
typedef float floatx4 __attribute__((ext_vector_type(4)));

static __device__ __forceinline__ unsigned short f2bf(float x) {
    union { float f; unsigned u; } a; a.f = x;
    unsigned r = a.u + 0x7fffu + ((a.u >> 16) & 1u);
    return (unsigned short)(r >> 16);
}
static __device__ __forceinline__ float bf2f(unsigned short x) {
    union { unsigned u; float f; } a; a.u = ((unsigned)x) << 16; return a.f;
}

// ---------------- f and g linear layers, fused in one launch ----------------
__global__ __launch_bounds__(640) void fg_fused(const float* __restrict__ enc,
                                                const float* __restrict__ Wenc,
                                                const float* __restrict__ benc,
                                                float* __restrict__ f,
                                                const float* __restrict__ pred,
                                                const float* __restrict__ Wpred,
                                                const float* __restrict__ bpred,
                                                float* __restrict__ g) {
    __shared__ float s[640 * 8];
    const bool isF = blockIdx.x < 128;
    const float* in   = isF ? enc : pred;
    const float* W    = isF ? Wenc : Wpred;
    const float* bias = isF ? benc : bpred;
    float* out        = isF ? f : g;
    const int H    = isF ? H1 : H2;
    const int Tdim = isF ? Tt : Uu;
    const int blk  = isF ? (int)blockIdx.x : (int)blockIdx.x - 128;
    const int tBlocks = Tdim >> 3;
    const int b  = blk / tBlocks;
    const int t0 = (blk % tBlocks) << 3;
    const float* inB = in + (size_t)b * H * Tdim + t0;
    const int tid = threadIdx.x;

    for (int h = tid; h < H; h += 640) {
        float4 v0 = *(const float4*)(inB + (size_t)h * Tdim);
        float4 v1 = *(const float4*)(inB + (size_t)h * Tdim + 4);
        *(float4*)(&s[h * 8])     = v0;
        *(float4*)(&s[h * 8 + 4]) = v1;
    }
    __syncthreads();

    const int d = tid;
    float acc[8];
    #pragma unroll
    for (int j = 0; j < 8; ++j) acc[j] = 0.f;
    #pragma unroll 4
    for (int h = 0; h < H; ++h) {
        float w = W[(size_t)h * Dd + d];
        float4 s0 = *(const float4*)(&s[h * 8]);
        float4 s1 = *(const float4*)(&s[h * 8 + 4]);
        acc[0] += s0.x * w; acc[1] += s0.y * w; acc[2] += s0.z * w; acc[3] += s0.w * w;
        acc[4] += s1.x * w; acc[5] += s1.y * w; acc[6] += s1.z * w; acc[7] += s1.w * w;
    }
    float bv = bias[d];
    float* o = out + ((size_t)b * Tdim + t0) * Dd + d;
    #pragma unroll
    for (int j = 0; j < 8; ++j) o[(size_t)j * Dd] = acc[j] + bv;
}

// ---------------- W_out -> Wb2 swizzled fragment layout + wtail ----------------
// Wb2[w][ksg][nt][l15][lg][8] (ushort): per-(wave,k-step) B-fragment order; each
// B-load instruction reads 1KB contiguous.
__global__ __launch_bounds__(256) void conv_wout2(const float* __restrict__ Wout,
                                                  unsigned short* __restrict__ Wb2,
                                                  float* __restrict__ wtail) {
    __shared__ float tile[32][128];
    const int blk = blockIdx.x;
    const int w = blk / 20;
    const int db = blk % 20;
    const int tid = threadIdx.x;

    #pragma unroll
    for (int i = 0; i < 16; ++i) {
        int idx = tid + 256 * i;
        int d_loc = idx >> 7;
        int v_loc = idx & 127;
        tile[d_loc][v_loc] = Wout[(size_t)(db * 32 + d_loc) * V1c + w * 128 + v_loc];
    }
    __syncthreads();

    #pragma unroll
    for (int k = 0; k < 2; ++k) {
        int gidx = tid * 2 + k;
        int nt  = gidx >> 6;
        int rem = gidx & 63;
        int l15 = rem >> 2;
        int lg  = rem & 3;
        int v_loc = nt * 16 + l15;
        ushort8 pk;
        #pragma unroll
        for (int j = 0; j < 8; ++j) pk[j] = f2bf(tile[lg * 8 + j][v_loc]);
        *(ushort8*)(Wb2 + (size_t)w * 81920 + db * 4096 + gidx * 8) = pk;
    }

    if (blk == 0) {
        for (int dd = tid; dd < Dd; dd += 256) wtail[dd] = Wout[(size_t)dd * V1c + 1024];
    }
}

// ---------------- fused joint + log-softmax ----------------
// 2048 blocks x 512 thr (8 waves). Block: 64 rows x 1025 cols; wave tile 64x128.
// = R12 (best: full-panel stage, 20-step K-loop on Wb2, post-K tail dot,
//   4x16-row LDS-staged NT drain) with ONE change: single-sweep softmax
//   (per-wave max+sumexp@max in one pass, exact LSE merge). pM/pS are
//   STANDALONE LDS (aliasing over hlds would race with tail-dot reads).
__global__ __launch_bounds__(512, 2) void joint_main(const float* __restrict__ f,
                                                     const float* __restrict__ g,
                                                     const unsigned short* __restrict__ Wb2,
                                                     const float* __restrict__ wtail,
                                                     const float* __restrict__ b_out,
                                                     float* __restrict__ out) {
    __shared__ __align__(16) union UU {
        unsigned short hlds[2 * 64 * 328];   // 83,968 B (two half-panels, stride 328)
        float sOut[16 * 1025];               // 65,600 B (aliases dead hlds)
    } u;
    __shared__ float wtld[640];
    __shared__ float pM[8 * 64];
    __shared__ float pS[8 * 64];
    __shared__ float sRed[64];
    __shared__ float sTail[64];

    const int tid = threadIdx.x;
    const int l = tid & 63;
    const int w = tid >> 6;
    const int l15 = l & 15;
    const int lg = l >> 4;

    const int blk = blockIdx.x;
    const int uhalf = blk & 1;
    const int t = (blk >> 1) & 255;
    const int b = blk >> 9;
    const int u0 = uhalf * 64;
    const size_t fbase = ((size_t)b * Tt + t) * Dd;
    const size_t gbase = ((size_t)b * Uu + u0) * Dd;
    const size_t rowbase = (size_t)(b * Tt + t) * Uu + u0;

    // stage wtail (fp32) into LDS
    for (int i = tid; i < Dd; i += 512) wtld[i] = wtail[i];

    floatx4 acc[4][8];
    #pragma unroll
    for (int i = 0; i < 4; ++i)
        #pragma unroll
        for (int j = 0; j < 8; ++j) acc[i][j] = (floatx4){0.f, 0.f, 0.f, 0.f};

    const unsigned short* __restrict__ bbase = Wb2 + (size_t)w * 81920 + (l15 * 32 + lg * 8);
    float tailAcc = 0.f;
    const int srow = w * 8 + (l >> 3);
    const int ssub = l & 7;

    // ---- stage FULL h = relu(f+g) panel: 64 rows x 640 cols bf16 ----
    {
        const int row = tid >> 3;
        const float* frow = f + fbase;
        const float* grow = g + gbase + (size_t)row * Dd;
        #pragma unroll
        for (int j = 0; j < 20; ++j) {
            int c4 = (tid & 7) + 8 * j;        // float4 slot 0..159
            int d = c4 * 4;
            int half = (j >= 10) ? 1 : 0;
            int cloc = c4 - half * 80;
            float4 fv = *(const float4*)(frow + d);
            float4 gv = *(const float4*)(grow + d);
            float h0 = fv.x + gv.x; h0 = h0 > 0.f ? h0 : 0.f;
            float h1 = fv.y + gv.y; h1 = h1 > 0.f ? h1 : 0.f;
            float h2 = fv.z + gv.z; h2 = h2 > 0.f ? h2 : 0.f;
            float h3 = fv.w + gv.w; h3 = h3 > 0.f ? h3 : 0.f;
            ushort4v pk;
            pk.x = f2bf(h0); pk.y = f2bf(h1); pk.z = f2bf(h2); pk.w = f2bf(h3);
            *(ushort4v*)(&u.hlds[half * 20992 + row * 328 + cloc * 4]) = pk;
        }
    }
    __syncthreads();

    // ---- K loop: 20 steps of 32, B double-buffered in regs, no barriers ----
    {
        ushort8 Bbuf[2][8];
        #pragma unroll
        for (int nt = 0; nt < 8; ++nt)
            Bbuf[0][nt] = *(const ushort8*)(bbase + nt * 512);
        #pragma unroll
        for (int ksg = 0; ksg < 20; ++ksg) {
            if (ksg < 19) {
                #pragma unroll
                for (int nt = 0; nt < 8; ++nt)
                    Bbuf[(ksg + 1) & 1][nt] =
                        *(const ushort8*)(bbase + (ksg + 1) * 4096 + nt * 512);
            }
            const int bufo = (ksg >= 10) ? 20992 : 0;
            const int ks = (ksg >= 10) ? (ksg - 10) : ksg;
            bf16x8 afrag[4];
            #pragma unroll
            for (int mt = 0; mt < 4; ++mt) {
                ushort8 av = *(const ushort8*)(&u.hlds[bufo + (mt * 16 + l15) * 328 + ks * 32 + lg * 8]);
                afrag[mt] = __builtin_bit_cast(bf16x8, av);
            }
            #pragma unroll
            for (int nt = 0; nt < 8; ++nt) {
                bf16x8 bfrag = __builtin_bit_cast(bf16x8, Bbuf[ksg & 1][nt]);
                #pragma unroll
                for (int mt = 0; mt < 4; ++mt) {
                    acc[mt][nt] = __builtin_amdgcn_mfma_f32_16x16x32_bf16(
                        afrag[mt], bfrag, acc[mt][nt], 0, 0, 0);
                }
            }
        }
    }

    // ---- tail column: dot(h_row, wtail) from LDS ----
    #pragma unroll
    for (int j = 0; j < 20; ++j) {
        int c4 = ssub + 8 * j;                 // 0..159
        int half = (j >= 10) ? 1 : 0;
        int cloc = c4 - half * 80;
        ushort4v hv = *(const ushort4v*)(&u.hlds[half * 20992 + srow * 328 + cloc * 4]);
        float4 wv = *(const float4*)(&wtld[c4 * 4]);
        tailAcc += bf2f(hv.x) * wv.x + bf2f(hv.y) * wv.y +
                   bf2f(hv.z) * wv.z + bf2f(hv.w) * wv.w;
    }

    tailAcc += __shfl_xor(tailAcc, 1);
    tailAcc += __shfl_xor(tailAcc, 2);
    tailAcc += __shfl_xor(tailAcc, 4);
    if (ssub == 0) sTail[srow] = tailAcc + b_out[1024];

    // ---- + b_out ----
    #pragma unroll
    for (int nt = 0; nt < 8; ++nt) {
        float bo = b_out[w * 128 + nt * 16 + l15];
        #pragma unroll
        for (int mt = 0; mt < 4; ++mt)
            #pragma unroll
            for (int r = 0; r < 4; ++r) acc[mt][nt][r] += bo;
    }

    // ---- single-sweep softmax: per-wave (max, sumexp@max) in ONE pass ----
    #pragma unroll
    for (int mt = 0; mt < 4; ++mt) {
        #pragma unroll
        for (int r = 0; r < 4; ++r) {
            int row = mt * 16 + lg * 4 + r;
            float m = acc[mt][0][r];
            #pragma unroll
            for (int nt = 1; nt < 8; ++nt) m = fmaxf(m, acc[mt][nt][r]);
            #pragma unroll
            for (int msk = 1; msk < 16; msk <<= 1) m = fmaxf(m, __shfl_xor(m, msk));
            float sv = 0.f;
            #pragma unroll
            for (int nt = 0; nt < 8; ++nt) sv += __expf(acc[mt][nt][r] - m);
            #pragma unroll
            for (int msk = 1; msk < 16; msk <<= 1) sv += __shfl_xor(sv, msk);
            if (l15 == 0) { pM[w * 64 + row] = m; pS[w * 64 + row] = sv; }
        }
    }
    __syncthreads();   // pM/pS + sTail visible

    if (tid < 64) {
        float tl = sTail[tid];
        float m = tl;
        #pragma unroll
        for (int c = 0; c < 8; ++c) m = fmaxf(m, pM[c * 64 + tid]);
        float sv = __expf(tl - m);
        #pragma unroll
        for (int c = 0; c < 8; ++c) sv += pS[c * 64 + tid] * __expf(pM[c * 64 + tid] - m);
        sRed[tid] = m + logf(sv);  // exact lse
    }
    __syncthreads();   // sRed ready; hlds dead -> sOut aliasing OK

    // ---- write: 4 groups of 16 rows (group g = acc[mt=g]), LDS-staged NT drain ----
    #pragma unroll
    for (int grp = 0; grp < 4; ++grp) {
        #pragma unroll
        for (int nt = 0; nt < 8; ++nt) {
            #pragma unroll
            for (int r = 0; r < 4; ++r) {
                u.sOut[(lg * 4 + r) * 1025 + w * 128 + nt * 16 + l15] =
                    acc[grp][nt][r] - sRed[grp * 16 + lg * 4 + r];
            }
        }
        if (tid < 16) u.sOut[tid * 1025 + 1024] = sTail[grp * 16 + tid] - sRed[grp * 16 + tid];
        __syncthreads();
        // 16*1025 = 16400 floats = 4100 float4
        float* outp = out + (rowbase + grp * 16) * (size_t)V1c;
        #pragma unroll
        for (int k = 0; k < 8; ++k) {
            int i4 = tid + 512 * k;
            floatx4 v = *(const floatx4*)(&u.sOut[4 * i4]);
            __builtin_nontemporal_store(v, (floatx4*)(outp + 4 * i4));
        }
        if (tid < 4) {
            int i4 = tid + 4096;
            floatx4 v = *(const floatx4*)(&u.sOut[4 * i4]);
            __builtin_nontemporal_store(v, (floatx4*)(outp + 4 * i4));
        }
        __syncthreads();
    }
}

extern "C" void kernel_launch(void* const* d_in, const int* in_sizes, int n_in,
                              void* d_out, int out_size, void* d_ws, size_t ws_size,
                              hipStream_t stream) {
    const float* enc   = (const float*)d_in[0];
    const float* pred  = (const float*)d_in[1];
    const float* Wenc  = (const float*)d_in[2];
    const float* benc  = (const float*)d_in[3];
    const float* Wpred = (const float*)d_in[4];
    const float* bpred = (const float*)d_in[5];
    const float* Wout  = (const float*)d_in[6];
    const float* bout  = (const float*)d_in[7];

    float* f = (float*)d_ws;                                     // 655360 f32
    float* g = f + (size_t)Bb * Tt * Dd;                         // 327680 f32
    unsigned short* Wb2 = (unsigned short*)(g + (size_t)Bb * Uu * Dd);  // 655360 u16
    float* wtail = (float*)(Wb2 + 8 * 81920);                    // 640 f32

    fg_fused<<<192, 640, 0, stream>>>(enc, Wenc, benc, f, pred, Wpred, bpred, g);
    conv_wout2<<<160, 256, 0, stream>>>(Wout, Wb2, wtail);
    joint_main<<<Bb * Tt * 2, 512, 0, stream>>>(f, g, Wb2, wtail, bout, (float*)d_out);
}